// Round 6
// baseline (332.659 us; speedup 1.0000x reference)
//
#include <hip/hip_runtime.h>
#include <hip/hip_bf16.h>
#include <stdint.h>

// HMPNN layer: two NNConv(sum-agg)+sigmoid, concat, Linear(32,32), sigmoid.
// R3: z-outer-product: msg[e,:] = z[e,:] @ W' (k=288), MFMA 16x16x32 bf16.
// R5/R6: device-scope fp32 atomics proved to be a ~1.45 TB/s memory-side RMW
//     wall (FETCH==WRITE==atomic volume in R3/R4). Fix: per-XCD private agg
//     copies (s_getreg HW_REG_XCC_ID) + WORKGROUP-scope atomicAdd -> RMW stays
//     in the XCD's 4MB L2 (agg copy = 3.2MB). Streams use nontemporal loads so
//     they don't evict agg lines. finalize sums the 8 copies.
//     (R6 = R5 with native-vector nontemporal loads; R5 failed to compile.)

#define NN 50000
#define EE 800000
#define AGGSZ ((size_t)NN * 16)   // floats per copy

typedef __attribute__((ext_vector_type(8))) short short8;
typedef __attribute__((ext_vector_type(4))) float f32x4;

union U8 { short8 v; unsigned int u[4]; };

__device__ __forceinline__ unsigned short f2bf_rne(float f) {
    union { float fl; unsigned int i; } v; v.fl = f;
    unsigned int x = v.i;
    x += 0x7FFFu + ((x >> 16) & 1u);
    return (unsigned short)(x >> 16);
}

__device__ __forceinline__ unsigned int pack2bf(float a, float b) {
    __hip_bfloat162 h = __float22bfloat162_rn(float2{a, b}); // x=low, y=high
    union { __hip_bfloat162 h2; unsigned int u; } c; c.h2 = h;
    return c.u;
}

// Wfrag[t][lane][j] = bf16( W'[32t + (lane>>4)*8 + j][lane&15] ), t=0..8.
__global__ void prep_w(const float* __restrict__ w_msg_a, const float* __restrict__ b_msg_a,
                       unsigned short* __restrict__ wf_a,
                       const float* __restrict__ w_msg_b, const float* __restrict__ b_msg_b,
                       unsigned short* __restrict__ wf_b) {
    const float* w_msg = blockIdx.x ? w_msg_b : w_msg_a;
    const float* b_msg = blockIdx.x ? b_msg_b : b_msg_a;
    unsigned short* wfrag = blockIdx.x ? wf_b : wf_a;
    for (int idx = threadIdx.x; idx < 9 * 64 * 8; idx += 256) {
        int j = idx & 7;
        int lane = (idx >> 3) & 63;
        int t = idx >> 9;
        int k = 32 * t + (lane >> 4) * 8 + j;
        int n = lane & 15;
        int f = k >> 4, i = k & 15;
        float v = (f < 16) ? w_msg[f * 256 + i * 16 + n]
                           : (f == 16 ? b_msg[i * 16 + n] : 0.f);
        wfrag[idx] = f2bf_rne(v);
    }
}

// 16 edges/wave-iter. Lane: m=lane&15 (edge row in A / o-col in D), quad=lane>>4.
// A-frag t elem j = bf16( attr[m, 2t+(quad>>1)] * xj[m, (quad&1)*8+j] ).
// aggc = base of 8 per-XCD copies; atomics are WORKGROUP scope -> local TCC.
__global__ __launch_bounds__(256) void edge_mfma(
    const int* __restrict__ eidx, const float* __restrict__ attr,
    const float* __restrict__ x, const unsigned short* __restrict__ wfrag,
    float* __restrict__ aggc)
{
    // HW_REG_XCC_ID = hwreg id 20, offset 0, size 4: encoding ((4-1)<<11)|20
    int xcc = (int)(__builtin_amdgcn_s_getreg((3 << 11) | 20) & 7u);
    float* __restrict__ agg = aggc + (size_t)xcc * AGGSZ;

    int lane = threadIdx.x & 63;
    int m = lane & 15, quad = lane >> 4;
    int q2 = quad >> 1, qb = quad & 1;
    int wave = (blockIdx.x * 256 + (int)threadIdx.x) >> 6;
    int nwaves = gridDim.x * 4;

    short8 bfr[9];
    #pragma unroll
    for (int t = 0; t < 9; ++t)
        bfr[t] = ((const short8*)wfrag)[t * 64 + lane];

    for (int g = wave; g < EE / 16; g += nwaves) {
        int ebase = g * 16;
        int src = __builtin_nontemporal_load(&eidx[ebase + m]);
        int dstr[4];
        #pragma unroll
        for (int r = 0; r < 4; ++r)
            dstr[r] = __builtin_nontemporal_load(&eidx[EE + ebase + quad * 4 + r]);

        const f32x4* xr = (const f32x4*)(x + (size_t)src * 16);
        f32x4 x0 = __builtin_nontemporal_load(xr + qb * 2);     // xj[m, qb*8+0..3]
        f32x4 x1 = __builtin_nontemporal_load(xr + qb * 2 + 1); // xj[m, qb*8+4..7]
        float xh[8] = {x0.x, x0.y, x0.z, x0.w, x1.x, x1.y, x1.z, x1.w};

        const float* ar = attr + (size_t)(ebase + m) * 16;
        float ah[8];
        #pragma unroll
        for (int t = 0; t < 8; ++t) ah[t] = __builtin_nontemporal_load(&ar[2 * t + q2]);

        f32x4 acc = {0.f, 0.f, 0.f, 0.f};
        #pragma unroll
        for (int t = 0; t < 8; ++t) {
            U8 a;
            #pragma unroll
            for (int jj = 0; jj < 4; ++jj)
                a.u[jj] = pack2bf(ah[t] * xh[2 * jj], ah[t] * xh[2 * jj + 1]);
            acc = __builtin_amdgcn_mfma_f32_16x16x32_bf16(a.v, bfr[t], acc, 0, 0, 0);
        }
        // t=8: k=256..287 -> bias row (q2==0: z=xj) / zero pad (q2==1)
        U8 a8;
        #pragma unroll
        for (int jj = 0; jj < 4; ++jj)
            a8.u[jj] = (q2 == 0) ? pack2bf(xh[2 * jj], xh[2 * jj + 1]) : 0u;
        acc = __builtin_amdgcn_mfma_f32_16x16x32_bf16(a8.v, bfr[8], acc, 0, 0, 0);

        #pragma unroll
        for (int r = 0; r < 4; ++r)
            __hip_atomic_fetch_add(&agg[(size_t)dstr[r] * 16 + m], acc[r],
                                   __ATOMIC_RELAXED, __HIP_MEMORY_SCOPE_WORKGROUP);
    }
}

// out[n,d] = sigmoid( h @ w_lin + b_lin ), h = sigmoid(sum_xcd agg + x@root + bias)
__global__ __launch_bounds__(256) void finalize(
    const float* __restrict__ xind,
    const float* __restrict__ aggc_a, const float* __restrict__ aggc_b,
    const float* __restrict__ root_a, const float* __restrict__ bias_a,
    const float* __restrict__ root_b, const float* __restrict__ bias_b,
    const float* __restrict__ w_lin, const float* __restrict__ b_lin,
    float* __restrict__ out)
{
    int tid = threadIdx.x;
    int n = blockIdx.x * 8 + (tid >> 5);
    if (n >= NN) return;
    int d = tid & 31;
    int lane = tid & 63;
    int gb32 = lane & ~31;

    float xv = xind[n * 16 + (d & 15)];

    int j = d & 15;
    const float* root = (d < 16) ? root_a : root_b;
    const float* bias = (d < 16) ? bias_a : bias_b;
    const float* aggc = (d < 16) ? aggc_a : aggc_b;

    float acc = bias[j];
    #pragma unroll
    for (int c = 0; c < 8; ++c)
        acc += aggc[(size_t)c * AGGSZ + n * 16 + j];
    #pragma unroll
    for (int i = 0; i < 16; ++i) {
        float xiv = __shfl(xv, gb32 + i);
        acc += xiv * root[i * 16 + j];
    }
    float h = 1.f / (1.f + __expf(-acc));

    float acc2 = b_lin[d];
    #pragma unroll
    for (int jj = 0; jj < 32; ++jj) {
        float hj = __shfl(h, gb32 + jj);
        acc2 += hj * w_lin[jj * 32 + d];
    }
    out[(size_t)n * 32 + d] = 1.f / (1.f + __expf(-acc2));
}

extern "C" void kernel_launch(void* const* d_in, const int* in_sizes, int n_in,
                              void* d_out, int out_size, void* d_ws, size_t ws_size,
                              hipStream_t stream) {
    (void)in_sizes; (void)n_in; (void)out_size; (void)ws_size;
    const float* x_indivi = (const float*)d_in[0];
    const float* x_src_a  = (const float*)d_in[1];
    const float* x_src_b  = (const float*)d_in[2];
    const int*   ei_a     = (const int*)d_in[3];
    const int*   ei_b     = (const int*)d_in[4];
    const float* ea_a     = (const float*)d_in[5];
    const float* ea_b     = (const float*)d_in[6];
    const float* w_msg_a  = (const float*)d_in[7];
    const float* b_msg_a  = (const float*)d_in[8];
    const float* root_a   = (const float*)d_in[9];
    const float* bias_a   = (const float*)d_in[10];
    const float* w_msg_b  = (const float*)d_in[11];
    const float* b_msg_b  = (const float*)d_in[12];
    const float* root_b   = (const float*)d_in[13];
    const float* bias_b   = (const float*)d_in[14];
    const float* w_lin    = (const float*)d_in[15];
    const float* b_lin    = (const float*)d_in[16];
    float* out = (float*)d_out;

    char* ws = (char*)d_ws;
    size_t off = 0;
    unsigned short* wf_a = (unsigned short*)(ws + off); off += 9 * 64 * 8 * 2;
    unsigned short* wf_b = (unsigned short*)(ws + off); off += 9 * 64 * 8 * 2;
    float* aggc_a = (float*)(ws + off); off += 8 * AGGSZ * 4;   // 25.6 MB (8 XCD copies)
    float* aggc_b = (float*)(ws + off); off += 8 * AGGSZ * 4;   // 25.6 MB

    (void)hipMemsetAsync(aggc_a, 0, 16 * AGGSZ * 4, stream);    // both copy sets
    prep_w<<<2, 256, 0, stream>>>(w_msg_a, b_msg_a, wf_a, w_msg_b, b_msg_b, wf_b);

    // split dispatches: per-XCD atomic working set = one 3.2MB copy (fits 4MB L2)
    edge_mfma<<<2048, 256, 0, stream>>>(ei_a, ea_a, x_src_a, wf_a, aggc_a);
    edge_mfma<<<2048, 256, 0, stream>>>(ei_b, ea_b, x_src_b, wf_b, aggc_b);

    finalize<<<(NN + 7) / 8, 256, 0, stream>>>(
        x_indivi, aggc_a, aggc_b, root_a, bias_a, root_b, bias_b, w_lin, b_lin, out);
}